// Round 18
// baseline (6782.064 us; speedup 1.0000x reference)
//
#include <hip/hip_runtime.h>
#include <math.h>

#define NB 32      // batch
#define NF 512     // feature_size
#define ND 256     // d_model
#define NT 32      // decode steps
#define RPB 32     // rows per attention tile
#define NTILE (NF / RPB)   // 16
#define NBLK (NB * NTILE)  // 512
#define XS 260     // xfer stride, float4-aligned

typedef __attribute__((ext_vector_type(8))) short bf16x8;
typedef __attribute__((ext_vector_type(4))) short bf16x4;
typedef __attribute__((ext_vector_type(4))) float f32x4;

__device__ __forceinline__ float sigmoidf_(float x) { return 1.0f / (1.0f + __expf(-x)); }

__device__ __forceinline__ short f2bf(float x) {
    union { float f; unsigned u; } v; v.f = x;
    unsigned r = (v.u + 0x7FFF + ((v.u >> 16) & 1)) >> 16;
    return (short)r;
}
__device__ __forceinline__ float bf2f(short s) {
    union { unsigned u; float f; } v;
    v.u = ((unsigned)(unsigned short)s) << 16;
    return v.f;
}

#define AGENT __HIP_MEMORY_SCOPE_AGENT
__device__ __forceinline__ float AL(const float* p) {
    return __hip_atomic_load(p, __ATOMIC_RELAXED, AGENT);
}
__device__ __forceinline__ void AS(float* p, float v) {
    __hip_atomic_store(p, v, __ATOMIC_RELAXED, AGENT);
}
__device__ __forceinline__ float2 AL2(const float* p) {
    unsigned long long v = __hip_atomic_load((const unsigned long long*)p, __ATOMIC_RELAXED, AGENT);
    union { unsigned long long u; float2 f; } cv; cv.u = v;
    return cv.f;
}
__device__ __forceinline__ void AS2(float* p, float x, float y) {
    union { unsigned long long u; float2 f; } cv;
    cv.f.x = x; cv.f.y = y;
    __hip_atomic_store((unsigned long long*)p, cv.u, __ATOMIC_RELAXED, AGENT);
}
__device__ __forceinline__ int APOLL(int* p) {
    return __hip_atomic_fetch_add(p, 0, __ATOMIC_RELAXED, AGENT);
}
__device__ __forceinline__ void SIGNAL(int* p, int tid, int coop) {
    asm volatile("s_waitcnt vmcnt(0)" ::: "memory");
    __syncthreads();
    if (coop && tid == 0) __hip_atomic_fetch_add(p, 1, __ATOMIC_RELAXED, AGENT);
}
__device__ __forceinline__ void WAITGE(int* p, int tgt, int tid) {
    if (tid == 0) {
        while (APOLL(p) < tgt) __builtin_amdgcn_s_sleep(8);
    }
    __syncthreads();
}

// ---------------- positional encoding q[F][D] ----------------
__global__ void pe_kernel(float* __restrict__ q) {
    int p = blockIdx.x;
    int d = threadIdx.x;
    float i2 = (float)((d >> 1) << 1);
    float rate = expf(-9.210340371976184f * (i2 / (float)ND));
    float ang = (float)p * rate;
    q[p * ND + d] = (d & 1) ? cosf(ang) : sinf(ang);
}

// ---------------- fp32 -> bf16 convert ----------------
__global__ void wcvt_kernel(const float* __restrict__ w, short* __restrict__ wb, int n) {
    int i = blockIdx.x * 256 + threadIdx.x;
    if (i < n) wb[i] = f2bf(w[i]);
}

// ---------------- weight prep ----------------
__global__ void wprep_kernel(const float* __restrict__ w_ih, const float* __restrict__ w_hh,
                             const float* __restrict__ w_h, const float* __restrict__ w_g,
                             float* __restrict__ wcat, float* __restrict__ w_hT,
                             float* __restrict__ w_gT) {
    int j = blockIdx.x;      // 0..1023
    int o = threadIdx.x;
    wcat[(size_t)j * 768 + o]       = w_ih[(size_t)j * 512 + o];
    wcat[(size_t)j * 768 + 256 + o] = w_ih[(size_t)j * 512 + 256 + o];
    wcat[(size_t)j * 768 + 512 + o] = w_hh[(size_t)j * 256 + o];
    if (j < ND)  w_hT[(size_t)j * ND + o] = w_h[(size_t)o * ND + j];
    if (j < 512) w_gT[(size_t)j * ND + o] = w_g[(size_t)o * 512 + j];
}

// ---------------- qwq[p][o] = dot(q[p,:], w_q[o,:]) ----------------
__global__ void qwq_kernel(const float* __restrict__ q, const float* __restrict__ w_q,
                           float* __restrict__ qwq) {
    int p = blockIdx.x;
    int o = threadIdx.x;
    __shared__ float qs[ND];
    qs[o] = q[(size_t)p * ND + o];
    __syncthreads();
    const float4* wr = (const float4*)(w_q + (size_t)o * ND);
    float acc = 0.f;
    for (int k4 = 0; k4 < ND / 4; ++k4) {
        float4 w = wr[k4];
        int k = 4 * k4;
        acc += qs[k] * w.x + qs[k + 1] * w.y + qs[k + 2] * w.z + qs[k + 3] * w.w;
    }
    qwq[(size_t)p * ND + o] = acc;
}

// ---------------- bsum = f@w_f^T + qwq ----------------
__global__ void base_kernel(const float* __restrict__ fin, const float* __restrict__ w_f,
                            const float* __restrict__ qwq, float* __restrict__ bsum) {
    int b = blockIdx.x / NTILE;
    int f0 = (blockIdx.x % NTILE) * RPB;
    int o = threadIdx.x;
    __shared__ float fs[RPB][ND];
    #pragma unroll
    for (int r = 0; r < RPB; ++r)
        fs[r][o] = fin[((size_t)(b * NF + f0 + r)) * ND + o];
    __syncthreads();
    float acc[RPB];
    #pragma unroll
    for (int r = 0; r < RPB; ++r) acc[r] = 0.f;
    const float4* wr = (const float4*)(w_f + (size_t)o * ND);
    for (int k4 = 0; k4 < ND / 4; ++k4) {
        float4 w = wr[k4];
        int k = 4 * k4;
        #pragma unroll
        for (int r = 0; r < RPB; ++r)
            acc[r] += fs[r][k] * w.x + fs[r][k + 1] * w.y + fs[r][k + 2] * w.z + fs[r][k + 3] * w.w;
    }
    #pragma unroll
    for (int r = 0; r < RPB; ++r)
        bsum[((size_t)(b * NF + f0 + r)) * ND + o] = acc[r] + qwq[(size_t)(f0 + r) * ND + o];
}

// ---------------- persistent decoder: reduced transport + hwh-once + 64b atomics ----------------
__global__ void __launch_bounds__(256, 2) dec_persist(
        int coop, int t0, int smask,
        const short* __restrict__ fin_bf, const int* __restrict__ ids,
        const float* __restrict__ emb, const short* __restrict__ q_bf,
        float* __restrict__ bsum,
        const float* __restrict__ wcat, const float* __restrict__ w_hT,
        const float* __restrict__ w_gT,
        const short* __restrict__ w_e_bf, const short* __restrict__ w_s_bf,
        float* __restrict__ h, float* __restrict__ cell,
        float* __restrict__ gatesT,
        float* __restrict__ cpart, float* __restrict__ cppart,
        float* __restrict__ cpz, float* __restrict__ hwhbuf,
        int* __restrict__ acount, int* __restrict__ gcount, int* __restrict__ hflag,
        int* __restrict__ rflag,
        float* __restrict__ out) {
    int bid = blockIdx.x;
    int tid = threadIdx.x;
    int l = tid & 63;
    int wv = tid >> 6;
    int c15 = l & 15;
    int g = l >> 4;
    int c = l;
    int b = bid >> 4;
    int tile = bid & 15;
    int f0 = tile * RPB;
    int o0 = wv * 64;

    __shared__ __align__(16) short tin_bf[RPB * ND];   // 16 KB
    __shared__ float xfer[RPB * XS];                   // 33.3 KB
    __shared__ float cred[2][1024];                    // 8 KB
    __shared__ float sred[RPB][5];
    char* tb = (char*)tin_bf;
    float* zl = xfer;            // [768]
    float* zp = xfer;            // [512]
    float* hn = xfer;            // [256]
    float* hwhl = xfer + 256;    // [256]

    const size_t CP = (size_t)NTILE * NB * ND;

    // persistent register copy of this block's bsum slice (coop mode)
    float4 bsv4[8];
    if (coop) {
        #pragma unroll
        for (int i = 0; i < 8; ++i) {
            int r = wv + 4 * i;
            bsv4[i] = *(const float4*)(bsum + ((size_t)(b * NF + f0 + r)) * ND + 4 * c);
        }
    }

    int tbeg = coop ? 0 : t0;
    int tend = coop ? NT : t0;

    for (int t = tbeg; t <= tend; ++t) {
        int prd = (t > 0) ? ((t - 1) & 1) : 0;

        // ===== GATES =====
        if ((smask & 1) && t < NT) {
            if (coop) {
                if (tid == 0) {
                    while (APOLL(&acount[b]) < 16 * t) __builtin_amdgcn_s_sleep(8);
                    while (APOLL(&hflag[b]) < t) __builtin_amdgcn_s_sleep(8);
                }
                __syncthreads();
            }
            // x segment (plain, cached)
            zl[tid] = emb[(size_t)ids[b * NT + t] * ND + tid];
            // cpsum segment
            if (!coop) {
                float cpsum = 0.f;
                if (t > 0) {
                    #pragma unroll
                    for (int tl = 0; tl < NTILE; ++tl)
                        cpsum += AL(&cppart[prd * CP + ((size_t)tl * NB + b) * ND + tid]);
                }
                zl[256 + tid] = cpsum;
            } else if (t == 0) {
                zl[256 + tid] = 0.f;
            }
            // h segment (64b atomic pairs)
            if (tid < 128) {
                float2 hv = AL2(&h[(size_t)(t & 1) * NB * ND + b * ND + 2 * tid]);
                zl[512 + 2 * tid]     = hv.x;
                zl[512 + 2 * tid + 1] = hv.y;
            }
            // tile0: single cppart reduction for the batch -> cpz + zl
            if (coop && t > 0 && tile == 0) {
                int half = tid >> 7, cp2 = tid & 127;
                float sx = 0.f, sy = 0.f;
                #pragma unroll
                for (int tl2 = 0; tl2 < 8; ++tl2) {
                    int tl = half * 8 + tl2;
                    float2 v = AL2(&cppart[prd * CP + ((size_t)tl * NB + b) * ND + 2 * cp2]);
                    sx += v.x; sy += v.y;
                }
                cred[half][2 * cp2]     = sx;
                cred[half][2 * cp2 + 1] = sy;
                __syncthreads();
                if (tid < 128) {
                    float rx = cred[0][2 * tid] + cred[1][2 * tid];
                    float ry = cred[0][2 * tid + 1] + cred[1][2 * tid + 1];
                    zl[256 + 2 * tid]     = rx;
                    zl[256 + 2 * tid + 1] = ry;
                    AS2(&cpz[(size_t)(t & 1) * NB * ND + b * ND + 2 * tid], rx, ry);
                }
                SIGNAL(&rflag[b], tid, coop);
            }
            __syncthreads();   // zl x/h (and tile0 cpsum) ready

            int j0 = tile * 64 + wv * 16;
            float s13[16];
            #pragma unroll
            for (int jj = 0; jj < 16; ++jj) {
                const float* wr = wcat + (size_t)(j0 + jj) * 768;
                float s = 0.f;
                #pragma unroll
                for (int i = 0; i < 4; ++i) s += wr[l + i * 64] * zl[l + i * 64];
                #pragma unroll
                for (int i = 8; i < 12; ++i) s += wr[l + i * 64] * zl[l + i * 64];
                s13[jj] = s;
            }
            if (coop && t > 0 && tile != 0) {
                WAITGE(&rflag[b], t, tid);
                if (tid < 128) {
                    float2 v = AL2(&cpz[(size_t)(t & 1) * NB * ND + b * ND + 2 * tid]);
                    zl[256 + 2 * tid]     = v.x;
                    zl[256 + 2 * tid + 1] = v.y;
                }
                __syncthreads();
            }
            #pragma unroll
            for (int jj = 0; jj < 16; ++jj) {
                const float* wr = wcat + (size_t)(j0 + jj) * 768;
                float s = s13[jj];
                #pragma unroll
                for (int i = 4; i < 8; ++i) s += wr[l + i * 64] * zl[l + i * 64];
                #pragma unroll
                for (int off2 = 1; off2 <= 32; off2 <<= 1)
                    s += __shfl_xor(s, off2);
                if (l == 0) AS(&gatesT[(size_t)b * 1024 + (j0 + jj)], s);
            }
            SIGNAL(&gcount[b], tid, coop);
        }

        // ===== POINTWISE + hwh (tile 0) =====
        if ((smask & 2) && t < NT && tile == 0) {
            if (coop) WAITGE(&gcount[b], 16 * (t + 1), tid);
            float gi = AL(&gatesT[(size_t)b * 1024 + tid]);
            float gf = AL(&gatesT[(size_t)b * 1024 + 256 + tid]);
            float gg = AL(&gatesT[(size_t)b * 1024 + 512 + tid]);
            float go = AL(&gatesT[(size_t)b * 1024 + 768 + tid]);
            float cold = cell[(size_t)b * ND + tid];
            float cnew = sigmoidf_(gf) * cold + sigmoidf_(gi) * tanhf(gg);
            float hval = sigmoidf_(go) * tanhf(cnew);
            cell[(size_t)b * ND + tid] = cnew;
            AS(&h[(size_t)((t + 1) & 1) * NB * ND + b * ND + tid], hval);
            hn[tid] = hval;
            __syncthreads();
            float a = 0.f;
            #pragma unroll 8
            for (int k = 0; k < ND; ++k)
                a += hn[k] * w_hT[(size_t)k * ND + tid];
            AS(&hwhbuf[(size_t)b * ND + tid], a);
            SIGNAL(&hflag[b], tid, coop);
        }

        // ===== PRED (tile 1, t>0) =====
        if ((smask & 2) && t > 0 && tile == 1) {
            if (coop && t == NT) {
                if (tid == 0) {
                    while (APOLL(&acount[b]) < 16 * t) __builtin_amdgcn_s_sleep(8);
                    while (APOLL(&hflag[b]) < t) __builtin_amdgcn_s_sleep(8);
                }
                __syncthreads();
            }
            if (tid < 128) {
                float sx = 0.f, sy = 0.f;
                #pragma unroll
                for (int tl = 0; tl < NTILE; ++tl) {
                    float2 v = AL2(&cpart[prd * CP + ((size_t)tl * NB + b) * ND + 2 * tid]);
                    sx += v.x; sy += v.y;
                }
                zp[2 * tid]     = sx;
                zp[2 * tid + 1] = sy;
            } else {
                int t2 = tid - 128;
                float2 hv = AL2(&h[(size_t)(t & 1) * NB * ND + b * ND + 2 * t2]);
                zp[256 + 2 * t2]     = hv.x;
                zp[256 + 2 * t2 + 1] = hv.y;
            }
            __syncthreads();
            float p = 0.f;
            #pragma unroll 8
            for (int k = 0; k < 512; ++k)
                p += zp[k] * w_gT[(size_t)k * ND + tid];
            out[((size_t)b * NT + (t - 1)) * ND + tid] = p;
            __syncthreads();
        }

        if (t >= NT) continue;

        // ===== A (attention) =====
        if (smask & 4) {
            if (coop) WAITGE(&hflag[b], t + 1, tid);
            if (tid < 128) {
                float2 hw = AL2(&hwhbuf[(size_t)b * ND + 2 * tid]);
                hwhl[2 * tid]     = hw.x;
                hwhl[2 * tid + 1] = hw.y;
            }
            __syncthreads();

            // phase 1: tin = tanh(hwh + bsv) -> bf16 swizzled
            {
                float4 hwh4 = *(const float4*)&hwhl[4 * c];
                #pragma unroll
                for (int i = 0; i < 8; ++i) {
                    int r = wv + 4 * i;
                    if (!coop)
                        bsv4[i] = *(const float4*)(bsum + ((size_t)(b * NF + f0 + r)) * ND + 4 * c);
                    bf16x4 tv;
                    tv.x = f2bf(tanhf(hwh4.x + bsv4[i].x));
                    tv.y = f2bf(tanhf(hwh4.y + bsv4[i].y));
                    tv.z = f2bf(tanhf(hwh4.z + bsv4[i].z));
                    tv.w = f2bf(tanhf(hwh4.w + bsv4[i].w));
                    *(bf16x4*)(tb + ((r * 512 + 8 * c) ^ ((r & 7) << 4))) = tv;
                }
            }
            __syncthreads();

            // phase 2: e = tin @ w_e^T via MFMA
            f32x4 acc[2][4];
            #pragma unroll
            for (int mt = 0; mt < 2; ++mt)
                #pragma unroll
                for (int nt = 0; nt < 4; ++nt)
                    acc[mt][nt] = (f32x4)0.f;
            #pragma unroll
            for (int ks = 0; ks < 8; ++ks) {
                int kb = ks * 32 + g * 8;
                bf16x8 afr[2];
                #pragma unroll
                for (int mt = 0; mt < 2; ++mt) {
                    int row = mt * 16 + c15;
                    afr[mt] = *(const bf16x8*)(tb + ((row * 512 + kb * 2) ^ ((row & 7) << 4)));
                }
                #pragma unroll
                for (int nt = 0; nt < 4; ++nt) {
                    int o = o0 + nt * 16 + c15;
                    bf16x8 bfr = *(const bf16x8*)(w_e_bf + (size_t)o * ND + kb);
                    #pragma unroll
                    for (int mt = 0; mt < 2; ++mt)
                        acc[mt][nt] = __builtin_amdgcn_mfma_f32_16x16x32_bf16(afr[mt], bfr, acc[mt][nt], 0, 0, 0);
                }
            }

            // phase 3: in-register softmax over cols
            {
                float ps[2][4];
                #pragma unroll
                for (int mt = 0; mt < 2; ++mt)
                    #pragma unroll
                    for (int reg = 0; reg < 4; ++reg) ps[mt][reg] = 0.f;
                #pragma unroll
                for (int mt = 0; mt < 2; ++mt)
                    #pragma unroll
                    for (int nt = 0; nt < 4; ++nt)
                        #pragma unroll
                        for (int reg = 0; reg < 4; ++reg) {
                            float a = __expf(acc[mt][nt][reg]);
                            acc[mt][nt][reg] = a;
                            ps[mt][reg] += a;
                        }
                #pragma unroll
                for (int off = 1; off <= 8; off <<= 1)
                    #pragma unroll
                    for (int mt = 0; mt < 2; ++mt)
                        #pragma unroll
                        for (int reg = 0; reg < 4; ++reg)
                            ps[mt][reg] += __shfl_xor(ps[mt][reg], off);
                if (c15 == 0) {
                    #pragma unroll
                    for (int mt = 0; mt < 2; ++mt)
                        #pragma unroll
                        for (int reg = 0; reg < 4; ++reg)
                            sred[mt * 16 + g * 4 + reg][wv] = ps[mt][reg];
                }
                __syncthreads();
                #pragma unroll
                for (int mt = 0; mt < 2; ++mt)
                    #pragma unroll
                    for (int reg = 0; reg < 4; ++reg) {
                        int r = mt * 16 + g * 4 + reg;
                        float inv = 1.0f / (sred[r][0] + sred[r][1] + sred[r][2] + sred[r][3]);
                        #pragma unroll
                        for (int nt = 0; nt < 4; ++nt)
                            acc[mt][nt][reg] *= inv;
                    }
            }

            // phase 4: alpha C-layout -> xfer
            #pragma unroll
            for (int mt = 0; mt < 2; ++mt)
                #pragma unroll
                for (int reg = 0; reg < 4; ++reg) {
                    int r = mt * 16 + g * 4 + reg;
                    #pragma unroll
                    for (int nt = 0; nt < 4; ++nt)
                        xfer[r * XS + o0 + nt * 16 + c15] = acc[mt][nt][reg];
                }
            __syncthreads();

            // phase 5a: c/cp partials (bf16 fin/q); alpha -> bf16 tin
            {
                float4 pc4 = {0.f, 0.f, 0.f, 0.f}, pcp4 = {0.f, 0.f, 0.f, 0.f};
                #pragma unroll
                for (int i = 0; i < 8; ++i) {
                    int r = wv + 4 * i;
                    float4 a4 = *(const float4*)&xfer[r * XS + 4 * c];
                    bf16x4 f4b = *(const bf16x4*)(fin_bf + ((size_t)(b * NF + f0 + r)) * ND + 4 * c);
                    bf16x4 q4b = *(const bf16x4*)(q_bf + ((size_t)(f0 + r)) * ND + 4 * c);
                    float fx = bf2f(f4b.x), fy = bf2f(f4b.y), fz = bf2f(f4b.z), fw = bf2f(f4b.w);
                    float qx = bf2f(q4b.x), qy = bf2f(q4b.y), qz = bf2f(q4b.z), qw = bf2f(q4b.w);
                    pc4.x += a4.x * fx;  pcp4.x += a4.x * (fx + qx);
                    pc4.y += a4.y * fy;  pcp4.y += a4.y * (fy + qy);
                    pc4.z += a4.z * fz;  pcp4.z += a4.z * (fz + qz);
                    pc4.w += a4.w * fw;  pcp4.w += a4.w * (fw + qw);
                    bf16x4 av;
                    av.x = f2bf(a4.x); av.y = f2bf(a4.y); av.z = f2bf(a4.z); av.w = f2bf(a4.w);
                    *(bf16x4*)(tb + ((r * 512 + 8 * c) ^ ((r & 7) << 4))) = av;
                }
                *(float4*)&cred[0][wv * 256 + 4 * c] = pc4;
                *(float4*)&cred[1][wv * 256 + 4 * c] = pcp4;
            }
            __syncthreads();

            // phase 5b: finalize c/cp partials (64b atomic pairs; half 0 -> cpart, half 1 -> cppart)
            {
                int half = tid >> 7;
                int cp2 = tid & 127;
                float sx = 0.f, sy = 0.f;
                #pragma unroll
                for (int w = 0; w < 4; ++w) {
                    sx += cred[half][w * 256 + 2 * cp2];
                    sy += cred[half][w * 256 + 2 * cp2 + 1];
                }
                float* dst = half ? cppart : cpart;
                AS2(&dst[(size_t)(t & 1) * CP + ((size_t)tile * NB + b) * ND + 2 * cp2], sx, sy);
            }

            // phase 6: alpha @ w_s^T via MFMA -> xfer
            {
                f32x4 acc2[2][4];
                #pragma unroll
                for (int mt = 0; mt < 2; ++mt)
                    #pragma unroll
                    for (int nt = 0; nt < 4; ++nt)
                        acc2[mt][nt] = (f32x4)0.f;
                #pragma unroll
                for (int ks = 0; ks < 8; ++ks) {
                    int kb = ks * 32 + g * 8;
                    bf16x8 afr[2];
                    #pragma unroll
                    for (int mt = 0; mt < 2; ++mt) {
                        int row = mt * 16 + c15;
                        afr[mt] = *(const bf16x8*)(tb + ((row * 512 + kb * 2) ^ ((row & 7) << 4)));
                    }
                    #pragma unroll
                    for (int nt = 0; nt < 4; ++nt) {
                        int o = o0 + nt * 16 + c15;
                        bf16x8 bfr = *(const bf16x8*)(w_s_bf + (size_t)o * ND + kb);
                        #pragma unroll
                        for (int mt = 0; mt < 2; ++mt)
                            acc2[mt][nt] = __builtin_amdgcn_mfma_f32_16x16x32_bf16(afr[mt], bfr, acc2[mt][nt], 0, 0, 0);
                    }
                }
                __syncthreads();
                #pragma unroll
                for (int mt = 0; mt < 2; ++mt)
                    #pragma unroll
                    for (int reg = 0; reg < 4; ++reg) {
                        int r = mt * 16 + g * 4 + reg;
                        #pragma unroll
                        for (int nt = 0; nt < 4; ++nt)
                            xfer[r * XS + o0 + nt * 16 + c15] = acc2[mt][nt][reg];
                    }
            }
            __syncthreads();

            // phase 7: bsv += xfer (registers in coop; store in fallback)
            #pragma unroll
            for (int i = 0; i < 8; ++i) {
                int r = wv + 4 * i;
                float4 x4 = *(const float4*)&xfer[r * XS + 4 * c];
                bsv4[i].x += x4.x;
                bsv4[i].y += x4.y;
                bsv4[i].z += x4.z;
                bsv4[i].w += x4.w;
                if (!coop)
                    *(float4*)(bsum + ((size_t)(b * NF + f0 + r)) * ND + 4 * c) = bsv4[i];
            }
            SIGNAL(&acount[b], tid, coop);
        }
    }
}

extern "C" void kernel_launch(void* const* d_in, const int* in_sizes, int n_in,
                              void* d_out, int out_size, void* d_ws, size_t ws_size,
                              hipStream_t stream) {
    const float* fin  = (const float*)d_in[0];
    const int*   ids  = (const int*)  d_in[1];
    const float* emb  = (const float*)d_in[2];
    const float* w_e  = (const float*)d_in[3];
    const float* w_h  = (const float*)d_in[4];
    const float* w_f  = (const float*)d_in[5];
    const float* w_q  = (const float*)d_in[6];
    const float* w_s  = (const float*)d_in[7];
    const float* w_g  = (const float*)d_in[8];
    const float* w_ih = (const float*)d_in[9];
    const float* w_hh = (const float*)d_in[10];
    float* out = (float*)d_out;
    float* ws  = (float*)d_ws;

    size_t off = 0;
    float* q      = ws + off; off += (size_t)NF * ND;
    float* qwq    = ws + off; off += (size_t)NF * ND;
    float* bsum   = ws + off; off += (size_t)NB * NF * ND;
    float* h      = ws + off; off += (size_t)2 * NB * ND;
    float* cell   = ws + off; off += (size_t)NB * ND;
    float* gatesT = ws + off; off += (size_t)NB * 1024;
    float* cpart  = ws + off; off += (size_t)2 * NTILE * NB * ND;
    float* cppart = ws + off; off += (size_t)2 * NTILE * NB * ND;
    float* cpz    = ws + off; off += (size_t)2 * NB * ND;
    float* hwhbuf = ws + off; off += (size_t)NB * ND;
    float* wcat   = ws + off; off += (size_t)1024 * 768;
    float* w_hT   = ws + off; off += (size_t)ND * ND;
    float* w_gT   = ws + off; off += (size_t)512 * ND;
    short* w_e_bf = (short*)(ws + off); off += (size_t)ND * ND / 2;
    short* w_s_bf = (short*)(ws + off); off += (size_t)ND * ND / 2;
    short* fin_bf = (short*)(ws + off); off += (size_t)NB * NF * ND / 2;
    short* q_bf   = (short*)(ws + off); off += (size_t)NF * ND / 2;
    int*   acount = (int*)(ws + off); off += 32;
    int*   gcount = (int*)(ws + off); off += 32;
    int*   hflag  = (int*)(ws + off); off += 32;
    int*   rflag  = (int*)(ws + off); off += 32;

    hipMemsetAsync(h, 0, sizeof(float) * NB * ND, stream);
    hipMemsetAsync(cell, 0, sizeof(float) * NB * ND, stream);
    hipMemsetAsync(acount, 0, sizeof(int) * 128, stream);

    pe_kernel<<<NF, ND, 0, stream>>>(q);
    wcvt_kernel<<<ND * ND / 256, 256, 0, stream>>>(w_e, w_e_bf, ND * ND);
    wcvt_kernel<<<ND * ND / 256, 256, 0, stream>>>(w_s, w_s_bf, ND * ND);
    wcvt_kernel<<<NB * NF * ND / 256, 256, 0, stream>>>(fin, fin_bf, NB * NF * ND);
    wcvt_kernel<<<NF * ND / 256, 256, 0, stream>>>(q, q_bf, NF * ND);
    wprep_kernel<<<1024, ND, 0, stream>>>(w_ih, w_hh, w_h, w_g, wcat, w_hT, w_gT);
    qwq_kernel<<<NF, ND, 0, stream>>>(q, w_q, qwq);
    base_kernel<<<NB * NTILE, ND, 0, stream>>>(fin, w_f, qwq, bsum);

    int coop1 = 1, t00 = 0, smask7 = 7;
    void* args[] = {
        (void*)&coop1, (void*)&t00, (void*)&smask7,
        (void*)&fin_bf, (void*)&ids, (void*)&emb, (void*)&q_bf, (void*)&bsum,
        (void*)&wcat, (void*)&w_hT, (void*)&w_gT,
        (void*)&w_e_bf, (void*)&w_s_bf,
        (void*)&h, (void*)&cell, (void*)&gatesT,
        (void*)&cpart, (void*)&cppart, (void*)&cpz, (void*)&hwhbuf,
        (void*)&acount, (void*)&gcount, (void*)&hflag, (void*)&rflag,
        (void*)&out
    };
    hipError_t e = hipLaunchCooperativeKernel((void*)dec_persist, dim3(NBLK), dim3(ND),
                                              args, 0, stream);
    if (e != hipSuccess) {
        for (int t = 0; t <= NT; ++t) {
            if (t < NT)
                dec_persist<<<NBLK, ND, 0, stream>>>(0, t, 1, fin_bf, ids, emb, q_bf, bsum,
                        wcat, w_hT, w_gT, w_e_bf, w_s_bf, h, cell, gatesT,
                        cpart, cppart, cpz, hwhbuf, acount, gcount, hflag, rflag, out);
            dec_persist<<<NBLK, ND, 0, stream>>>(0, t, 2, fin_bf, ids, emb, q_bf, bsum,
                    wcat, w_hT, w_gT, w_e_bf, w_s_bf, h, cell, gatesT,
                    cpart, cppart, cpz, hwhbuf, acount, gcount, hflag, rflag, out);
            if (t < NT)
                dec_persist<<<NBLK, ND, 0, stream>>>(0, t, 4, fin_bf, ids, emb, q_bf, bsum,
                        wcat, w_hT, w_gT, w_e_bf, w_s_bf, h, cell, gatesT,
                        cpart, cppart, cpz, hwhbuf, acount, gcount, hflag, rflag, out);
        }
    }
}

// Round 19
// 2911.876 us; speedup vs baseline: 2.3291x; 2.3291x over previous
//
#include <hip/hip_runtime.h>
#include <math.h>

#define NB 32      // batch
#define NF 512     // feature_size
#define ND 256     // d_model
#define NT 32      // decode steps
#define RPB 32     // rows per attention tile
#define NTILE (NF / RPB)   // 16
#define NBLK (NB * NTILE)  // 512

typedef __attribute__((ext_vector_type(8))) short bf16x8;
typedef __attribute__((ext_vector_type(4))) short bf16x4;
typedef __attribute__((ext_vector_type(4))) float f32x4;

__device__ __forceinline__ float sigmoidf_(float x) { return 1.0f / (1.0f + __expf(-x)); }

__device__ __forceinline__ short f2bf(float x) {
    union { float f; unsigned u; } v; v.f = x;
    unsigned r = (v.u + 0x7FFF + ((v.u >> 16) & 1)) >> 16;
    return (short)r;
}
__device__ __forceinline__ float bf2f(short s) {
    union { unsigned u; float f; } v;
    v.u = ((unsigned)(unsigned short)s) << 16;
    return v.f;
}

// ---------------- positional encoding q[F][D] ----------------
__global__ void pe_kernel(float* __restrict__ q) {
    int p = blockIdx.x;
    int d = threadIdx.x;
    float i2 = (float)((d >> 1) << 1);
    float rate = expf(-9.210340371976184f * (i2 / (float)ND));
    float ang = (float)p * rate;
    q[p * ND + d] = (d & 1) ? cosf(ang) : sinf(ang);
}

// ---------------- fp32 -> bf16 convert ----------------
__global__ void wcvt_kernel(const float* __restrict__ w, short* __restrict__ wb, int n) {
    int i = blockIdx.x * 256 + threadIdx.x;
    if (i < n) wb[i] = f2bf(w[i]);
}

// ---------------- transposes: w_hT[k][o], w_gT[k][o] ----------------
__global__ void wprep_kernel(const float* __restrict__ w_h, const float* __restrict__ w_g,
                             float* __restrict__ w_hT, float* __restrict__ w_gT) {
    int k = blockIdx.x;      // 0..511
    int o = threadIdx.x;
    if (k < ND) w_hT[(size_t)k * ND + o] = w_h[(size_t)o * ND + k];
    w_gT[(size_t)k * ND + o] = w_g[(size_t)o * 512 + k];
}

// ---------------- qwq[p][o] = dot(q[p,:], w_q[o,:]) ----------------
__global__ void qwq_kernel(const float* __restrict__ q, const float* __restrict__ w_q,
                           float* __restrict__ qwq) {
    int p = blockIdx.x;
    int o = threadIdx.x;
    __shared__ float qs[ND];
    qs[o] = q[(size_t)p * ND + o];
    __syncthreads();
    const float4* wr = (const float4*)(w_q + (size_t)o * ND);
    float acc = 0.f;
    for (int k4 = 0; k4 < ND / 4; ++k4) {
        float4 w = wr[k4];
        int k = 4 * k4;
        acc += qs[k] * w.x + qs[k + 1] * w.y + qs[k + 2] * w.z + qs[k + 3] * w.w;
    }
    qwq[(size_t)p * ND + o] = acc;
}

// ---------------- base -> bsum_cl (C-fragment-linearized layout) ----------------
// element (r, o) of block blk: owner_tid = (o&0xC0) + (r&12)*4 + (o&15);
// j = (r>>4)*16 + ((o>>4)&3)*4 + (r&3);  flat = blk*8192 + owner_tid*32 + j
__global__ void base_kernel(const float* __restrict__ fin, const float* __restrict__ w_f,
                            const float* __restrict__ qwq, float* __restrict__ bsum_cl) {
    int blk = blockIdx.x;
    int b = blk / NTILE;
    int f0 = (blk % NTILE) * RPB;
    int o = threadIdx.x;
    __shared__ float fs[RPB][ND];
    #pragma unroll
    for (int r = 0; r < RPB; ++r)
        fs[r][o] = fin[((size_t)(b * NF + f0 + r)) * ND + o];
    __syncthreads();
    float acc[RPB];
    #pragma unroll
    for (int r = 0; r < RPB; ++r) acc[r] = 0.f;
    const float4* wr = (const float4*)(w_f + (size_t)o * ND);
    for (int k4 = 0; k4 < ND / 4; ++k4) {
        float4 w = wr[k4];
        int k = 4 * k4;
        #pragma unroll
        for (int r = 0; r < RPB; ++r)
            acc[r] += fs[r][k] * w.x + fs[r][k + 1] * w.y + fs[r][k + 2] * w.z + fs[r][k + 3] * w.w;
    }
    #pragma unroll
    for (int r = 0; r < RPB; ++r) {
        int owner = (o & 0xC0) + (r & 12) * 4 + (o & 15);
        int j = (r >> 4) * 16 + ((o >> 4) & 3) * 4 + (r & 3);
        bsum_cl[(size_t)blk * 8192 + owner * 32 + j] = acc[r] + qwq[(size_t)(f0 + r) * ND + o];
    }
}

// ---------------- fin/q -> C-layout bf16 ----------------
__global__ void clprep_kernel(const float* __restrict__ fin, const float* __restrict__ qpe,
                              short* __restrict__ fin_cl, short* __restrict__ q_cl) {
    int blk = blockIdx.x;
    int b = blk >> 4;
    int tile = blk & 15;
    int f0 = tile * RPB;
    int tid = threadIdx.x;
    int g = (tid & 63) >> 4;
    int c15 = tid & 15;
    int o0 = tid & 0xC0;
    #pragma unroll
    for (int j = 0; j < 32; ++j) {
        int mt = j >> 4, nt = (j >> 2) & 3, reg = j & 3;
        int r = mt * 16 + g * 4 + reg;
        int col = o0 + nt * 16 + c15;
        fin_cl[(size_t)blk * 8192 + tid * 32 + j] =
            f2bf(fin[((size_t)(b * NF + f0 + r)) * ND + col]);
        if (b == 0)
            q_cl[(size_t)tile * 8192 + tid * 32 + j] =
                f2bf(qpe[(size_t)(f0 + r) * ND + col]);
    }
}

// ---------------- gates + pred (round-13 validated) ----------------
#define ZSTRIDE 769
__global__ void gates_kernel(int t, int mode,
                             const int* __restrict__ ids, const float* __restrict__ emb,
                             const float* __restrict__ cpart, const float* __restrict__ cppart,
                             const float* __restrict__ h,
                             const float* __restrict__ w_ih, const float* __restrict__ w_hh,
                             const float* __restrict__ w_gT,
                             float* __restrict__ gatesT, float* __restrict__ out) {
    extern __shared__ float lds[];
    int bid = blockIdx.x;
    int tid = threadIdx.x;

    if (bid < 128) {
        if (!(mode & 1)) return;
        int j0 = bid * 8;
        float* wl = lds;              // [8][768]
        float* zl = lds + 8 * 768;    // [32][ZSTRIDE]
        float4* wl4 = (float4*)wl;
        for (int cc = 0; cc < 6; ++cc) {
            int idx4 = tid + cc * 256;
            int flat = idx4 * 4;
            int r = flat / 768;
            int col = flat - r * 768;
            float4 v;
            if (col < 512) v = *(const float4*)(w_ih + (size_t)(j0 + r) * 512 + col);
            else           v = *(const float4*)(w_hh + (size_t)(j0 + r) * 256 + (col - 512));
            wl4[idx4] = v;
        }
        for (int b = 0; b < NB; ++b) {
            int d = tid;
            float xv = (t < NT) ? emb[(size_t)ids[b * NT + t] * ND + d] : 0.f;
            float cpsum = 0.f;
            if (t > 0) {
                #pragma unroll
                for (int tl = 0; tl < NTILE; ++tl)
                    cpsum += cppart[((size_t)tl * NB + b) * ND + d];
            }
            float hv = h[(size_t)b * ND + d];
            zl[b * ZSTRIDE + d]       = xv;
            zl[b * ZSTRIDE + 256 + d] = cpsum;
            zl[b * ZSTRIDE + 512 + d] = hv;
        }
        __syncthreads();
        int r = tid >> 5;
        int b = tid & 31;
        const float4* wr4 = (const float4*)(wl + r * 768);
        const float* zb = zl + b * ZSTRIDE;
        float acc = 0.f;
        #pragma unroll 8
        for (int k4 = 0; k4 < 192; ++k4) {
            float4 w = wr4[k4];
            int k = 4 * k4;
            acc += w.x * zb[k] + w.y * zb[k + 1] + w.z * zb[k + 2] + w.w * zb[k + 3];
        }
        gatesT[(size_t)b * 1024 + (j0 + r)] = acc;
    } else {
        if (!(mode & 2)) return;
        int b = bid - 128;
        float* zp = lds;              // [512]
        float csum = 0.f;
        #pragma unroll
        for (int tl = 0; tl < NTILE; ++tl)
            csum += cpart[((size_t)tl * NB + b) * ND + tid];
        zp[tid] = csum;
        zp[256 + tid] = h[(size_t)b * ND + tid];
        __syncthreads();
        float p = 0.f;
        #pragma unroll 8
        for (int k = 0; k < 512; ++k)
            p += zp[k] * w_gT[(size_t)k * ND + tid];
        out[((size_t)b * NT + (t - 1)) * ND + tid] = p;
    }
}

// ---------------- attention step, all C-layout, no xfer buffer ----------------
__global__ void __launch_bounds__(256, 3) attn_step_kernel(
        float* __restrict__ bsum_cl,
        const short* __restrict__ fin_cl, const short* __restrict__ q_cl,
        const float* __restrict__ gatesT,
        const float* __restrict__ cell_prev, float* __restrict__ cell_next,
        float* __restrict__ h_next,
        const float* __restrict__ w_hT,
        const short* __restrict__ w_e_bf, const short* __restrict__ w_s_bf,
        float* __restrict__ cpart, float* __restrict__ cppart) {
    int blk = blockIdx.x;
    int b = blk / NTILE;
    int tile = blk % NTILE;
    int tid = threadIdx.x;
    int l = tid & 63;
    int c15 = l & 15;
    int g = l >> 4;
    int o0 = tid & 0xC0;

    __shared__ __align__(16) short tin_bf[RPB * ND];   // 16 KB
    __shared__ float hn[ND];
    __shared__ float hwhl[ND];
    __shared__ float sred[RPB][5];
    char* tb = (char*)tin_bf;

    // ---- phase 0: LSTM pointwise + hwh GEMV ----
    {
        float gi = gatesT[(size_t)b * 1024 + tid];
        float gf = gatesT[(size_t)b * 1024 + 256 + tid];
        float gg = gatesT[(size_t)b * 1024 + 512 + tid];
        float go = gatesT[(size_t)b * 1024 + 768 + tid];
        float cold = cell_prev[(size_t)b * ND + tid];
        float cnew = sigmoidf_(gf) * cold + sigmoidf_(gi) * tanhf(gg);
        float hval = sigmoidf_(go) * tanhf(cnew);
        if (tile == 0) {
            cell_next[(size_t)b * ND + tid] = cnew;
            h_next[(size_t)b * ND + tid] = hval;
        }
        hn[tid] = hval;
    }
    __syncthreads();
    {
        float a = 0.f;
        #pragma unroll 8
        for (int k = 0; k < ND; ++k)
            a += hn[k] * w_hT[(size_t)k * ND + tid];
        hwhl[tid] = a;
    }
    __syncthreads();

    // ---- phase 1: bsv (C-layout float4s) ; tin = tanh(hwh+bsv) -> swizzled bf16 ----
    f32x4 bsv[2][4];
    {
        float hw4[4];
        #pragma unroll
        for (int nt = 0; nt < 4; ++nt)
            hw4[nt] = hwhl[o0 + nt * 16 + c15];
        const f32x4* bsp = (const f32x4*)(bsum_cl + (size_t)blk * 8192 + tid * 32);
        #pragma unroll
        for (int mt = 0; mt < 2; ++mt)
            #pragma unroll
            for (int nt = 0; nt < 4; ++nt) {
                f32x4 bv = bsp[mt * 4 + nt];
                bsv[mt][nt] = bv;
                int col = o0 + nt * 16 + c15;
                #pragma unroll
                for (int reg = 0; reg < 4; ++reg) {
                    int r = mt * 16 + g * 4 + reg;
                    float tv = tanhf(hw4[nt] + bv[reg]);
                    *(short*)(tb + ((r * 512 + col * 2) ^ ((r & 7) << 4))) = f2bf(tv);
                }
            }
    }
    __syncthreads();

    // ---- phase 2: e = tin @ w_e^T via MFMA ----
    f32x4 acc[2][4];
    #pragma unroll
    for (int mt = 0; mt < 2; ++mt)
        #pragma unroll
        for (int nt = 0; nt < 4; ++nt)
            acc[mt][nt] = (f32x4)0.f;
    #pragma unroll
    for (int ks = 0; ks < 8; ++ks) {
        int kb = ks * 32 + g * 8;
        bf16x8 afr[2];
        #pragma unroll
        for (int mt = 0; mt < 2; ++mt) {
            int row = mt * 16 + c15;
            afr[mt] = *(const bf16x8*)(tb + ((row * 512 + kb * 2) ^ ((row & 7) << 4)));
        }
        #pragma unroll
        for (int nt = 0; nt < 4; ++nt) {
            int o = o0 + nt * 16 + c15;
            bf16x8 bfr = *(const bf16x8*)(w_e_bf + (size_t)o * ND + kb);
            #pragma unroll
            for (int mt = 0; mt < 2; ++mt)
                acc[mt][nt] = __builtin_amdgcn_mfma_f32_16x16x32_bf16(afr[mt], bfr, acc[mt][nt], 0, 0, 0);
        }
    }

    // ---- phase 3: in-register softmax over cols ----
    {
        float ps[2][4];
        #pragma unroll
        for (int mt = 0; mt < 2; ++mt)
            #pragma unroll
            for (int reg = 0; reg < 4; ++reg) ps[mt][reg] = 0.f;
        #pragma unroll
        for (int mt = 0; mt < 2; ++mt)
            #pragma unroll
            for (int nt = 0; nt < 4; ++nt)
                #pragma unroll
                for (int reg = 0; reg < 4; ++reg) {
                    float a = __expf(acc[mt][nt][reg]);
                    acc[mt][nt][reg] = a;
                    ps[mt][reg] += a;
                }
        #pragma unroll
        for (int off = 1; off <= 8; off <<= 1)
            #pragma unroll
            for (int mt = 0; mt < 2; ++mt)
                #pragma unroll
                for (int reg = 0; reg < 4; ++reg)
                    ps[mt][reg] += __shfl_xor(ps[mt][reg], off);
        if (c15 == 0) {
            #pragma unroll
            for (int mt = 0; mt < 2; ++mt)
                #pragma unroll
                for (int reg = 0; reg < 4; ++reg)
                    sred[mt * 16 + g * 4 + reg][tid >> 6] = ps[mt][reg];
        }
        __syncthreads();
        #pragma unroll
        for (int mt = 0; mt < 2; ++mt)
            #pragma unroll
            for (int reg = 0; reg < 4; ++reg) {
                int r = mt * 16 + g * 4 + reg;
                float inv = 1.0f / (sred[r][0] + sred[r][1] + sred[r][2] + sred[r][3]);
                #pragma unroll
                for (int nt = 0; nt < 4; ++nt)
                    acc[mt][nt][reg] *= inv;   // acc = alpha
            }
    }

    // ---- phase 4: alpha -> swizzled bf16 tin (C-layout scatter, validated r7/8) ----
    #pragma unroll
    for (int mt = 0; mt < 2; ++mt)
        #pragma unroll
        for (int reg = 0; reg < 4; ++reg) {
            int r = mt * 16 + g * 4 + reg;
            #pragma unroll
            for (int nt = 0; nt < 4; ++nt) {
                int col = o0 + nt * 16 + c15;
                *(short*)(tb + ((r * 512 + col * 2) ^ ((r & 7) << 4))) = f2bf(acc[mt][nt][reg]);
            }
        }

    // ---- phase 5: c/cp partials from C-layout (bf16 fin_cl/q_cl; shfl row-reduce, validated r7/8) ----
    {
        const bf16x8* fp = (const bf16x8*)(fin_cl + (size_t)blk * 8192 + tid * 32);
        const bf16x8* qp = (const bf16x8*)(q_cl + (size_t)tile * 8192 + tid * 32);
        short fb[32], qb[32];
        #pragma unroll
        for (int i8 = 0; i8 < 4; ++i8) {
            bf16x8 fv8 = fp[i8];
            bf16x8 qv8 = qp[i8];
            #pragma unroll
            for (int sl = 0; sl < 8; ++sl) { fb[i8 * 8 + sl] = fv8[sl]; qb[i8 * 8 + sl] = qv8[sl]; }
        }
        float pc[4], pcp[4];
        #pragma unroll
        for (int nt = 0; nt < 4; ++nt) { pc[nt] = 0.f; pcp[nt] = 0.f; }
        #pragma unroll
        for (int mt = 0; mt < 2; ++mt)
            #pragma unroll
            for (int nt = 0; nt < 4; ++nt)
                #pragma unroll
                for (int reg = 0; reg < 4; ++reg) {
                    int j = mt * 16 + nt * 4 + reg;
                    float a = acc[mt][nt][reg];
                    float fv = bf2f(fb[j]);
                    float qv = bf2f(qb[j]);
                    pc[nt] += a * fv;
                    pcp[nt] += a * (fv + qv);
                }
        #pragma unroll
        for (int off = 16; off <= 32; off <<= 1)
            #pragma unroll
            for (int nt = 0; nt < 4; ++nt) {
                pc[nt]  += __shfl_xor(pc[nt], off);
                pcp[nt] += __shfl_xor(pcp[nt], off);
            }
        if (g == 0) {
            #pragma unroll
            for (int nt = 0; nt < 4; ++nt) {
                int col = o0 + nt * 16 + c15;
                cpart [((size_t)tile * NB + b) * ND + col] = pc[nt];
                cppart[((size_t)tile * NB + b) * ND + col] = pcp[nt];
            }
        }
    }
    __syncthreads();   // alpha writes (ph4) visible before phase-6 MFMA reads

    // ---- phase 6: alpha @ w_s^T via MFMA; bsv += ; coalesced C-layout store ----
    {
        f32x4 acc2[2][4];
        #pragma unroll
        for (int mt = 0; mt < 2; ++mt)
            #pragma unroll
            for (int nt = 0; nt < 4; ++nt)
                acc2[mt][nt] = (f32x4)0.f;
        #pragma unroll
        for (int ks = 0; ks < 8; ++ks) {
            int kb = ks * 32 + g * 8;
            bf16x8 afr[2];
            #pragma unroll
            for (int mt = 0; mt < 2; ++mt) {
                int row = mt * 16 + c15;
                afr[mt] = *(const bf16x8*)(tb + ((row * 512 + kb * 2) ^ ((row & 7) << 4)));
            }
            #pragma unroll
            for (int nt = 0; nt < 4; ++nt) {
                int o = o0 + nt * 16 + c15;
                bf16x8 bfr = *(const bf16x8*)(w_s_bf + (size_t)o * ND + kb);
                #pragma unroll
                for (int mt = 0; mt < 2; ++mt)
                    acc2[mt][nt] = __builtin_amdgcn_mfma_f32_16x16x32_bf16(afr[mt], bfr, acc2[mt][nt], 0, 0, 0);
            }
        }
        f32x4* bsp = (f32x4*)(bsum_cl + (size_t)blk * 8192 + tid * 32);
        #pragma unroll
        for (int mt = 0; mt < 2; ++mt)
            #pragma unroll
            for (int nt = 0; nt < 4; ++nt) {
                f32x4 v = bsv[mt][nt];
                v += acc2[mt][nt];
                bsp[mt * 4 + nt] = v;
            }
    }
}

extern "C" void kernel_launch(void* const* d_in, const int* in_sizes, int n_in,
                              void* d_out, int out_size, void* d_ws, size_t ws_size,
                              hipStream_t stream) {
    const float* fin  = (const float*)d_in[0];
    const int*   ids  = (const int*)  d_in[1];
    const float* emb  = (const float*)d_in[2];
    const float* w_e  = (const float*)d_in[3];
    const float* w_h  = (const float*)d_in[4];
    const float* w_f  = (const float*)d_in[5];
    const float* w_q  = (const float*)d_in[6];
    const float* w_s  = (const float*)d_in[7];
    const float* w_g  = (const float*)d_in[8];
    const float* w_ih = (const float*)d_in[9];
    const float* w_hh = (const float*)d_in[10];
    float* out = (float*)d_out;
    float* ws  = (float*)d_ws;

    size_t off = 0;
    float* q       = ws + off; off += (size_t)NF * ND;
    float* qwq     = ws + off; off += (size_t)NF * ND;
    float* bsum_cl = ws + off; off += (size_t)NB * NF * ND;       // C-layout
    float* h0      = ws + off; off += (size_t)NB * ND;
    float* h1      = ws + off; off += (size_t)NB * ND;
    float* cell0   = ws + off; off += (size_t)NB * ND;
    float* cell1   = ws + off; off += (size_t)NB * ND;
    float* gatesT  = ws + off; off += (size_t)NB * 1024;
    float* cpart   = ws + off; off += (size_t)NTILE * NB * ND;
    float* cppart  = ws + off; off += (size_t)NTILE * NB * ND;
    float* w_hT    = ws + off; off += (size_t)ND * ND;
    float* w_gT    = ws + off; off += (size_t)512 * ND;
    short* w_e_bf  = (short*)(ws + off); off += (size_t)ND * ND / 2;
    short* w_s_bf  = (short*)(ws + off); off += (size_t)ND * ND / 2;
    short* fin_cl  = (short*)(ws + off); off += (size_t)NB * NF * ND / 2;
    short* q_cl    = (short*)(ws + off); off += (size_t)NF * ND / 2;

    float* hbuf[2]    = { h0, h1 };
    float* cellbuf[2] = { cell0, cell1 };

    hipMemsetAsync(h0, 0, sizeof(float) * NB * ND, stream);
    hipMemsetAsync(cell0, 0, sizeof(float) * NB * ND, stream);

    pe_kernel<<<NF, ND, 0, stream>>>(q);
    wcvt_kernel<<<ND * ND / 256, 256, 0, stream>>>(w_e, w_e_bf, ND * ND);
    wcvt_kernel<<<ND * ND / 256, 256, 0, stream>>>(w_s, w_s_bf, ND * ND);
    wprep_kernel<<<512, ND, 0, stream>>>(w_h, w_g, w_hT, w_gT);
    qwq_kernel<<<NF, ND, 0, stream>>>(q, w_q, qwq);
    base_kernel<<<NBLK, ND, 0, stream>>>(fin, w_f, qwq, bsum_cl);
    clprep_kernel<<<NBLK, ND, 0, stream>>>(fin, q, fin_cl, q_cl);

    const size_t gates_lds = (size_t)(8 * 768 + NB * ZSTRIDE) * sizeof(float);  // 123008 B

    for (int t = 0; t < NT; ++t) {
        int mode = (t > 0) ? 3 : 1;
        int p = t & 1;
        gates_kernel<<<160, ND, gates_lds, stream>>>(t, mode, ids, emb, cpart, cppart, hbuf[p],
                                                     w_ih, w_hh, w_gT, gatesT, out);
        attn_step_kernel<<<NBLK, ND, 0, stream>>>(bsum_cl, fin_cl, q_cl, gatesT,
                                                  cellbuf[p], cellbuf[p ^ 1], hbuf[p ^ 1],
                                                  w_hT, w_e_bf, w_s_bf, cpart, cppart);
    }
    // final pred for t = NT-1 (h(NT-1) lives in hbuf[NT&1] = hbuf[0])
    gates_kernel<<<160, ND, gates_lds, stream>>>(NT, 2, ids, emb, cpart, cppart, hbuf[0],
                                                 w_ih, w_hh, w_gT, gatesT, out);
}